// Round 3
// baseline (681.576 us; speedup 1.0000x reference)
//
#include <hip/hip_runtime.h>
#include <hip/hip_bf16.h>

typedef __bf16 bf16x8 __attribute__((ext_vector_type(8)));
typedef float floatx4 __attribute__((ext_vector_type(4)));

__device__ __forceinline__ unsigned short f2bf(float f) {
  unsigned u = __float_as_uint(f);
  u += 0x7fffu + ((u >> 16) & 1u);   // RNE; inputs finite
  return (unsigned short)(u >> 16);
}

__device__ __forceinline__ unsigned cvt_pk_bf16(float lo, float hi) {
  unsigned r;
  asm("v_cvt_pk_bf16_f32 %0, %1, %2" : "=v"(r) : "v"(lo), "v"(hi));
  return r;   // r.lo16 = bf16(lo), r.hi16 = bf16(hi)
}

__device__ __forceinline__ void async_copy16(const void* g, void* l) {
  __builtin_amdgcn_global_load_lds(
      (const __attribute__((address_space(1))) void*)g,
      (__attribute__((address_space(3))) void*)l, 16, 0, 0);
}

// ------------- elementwise fp32 -> bf16 (8 elems/thread) -------------
__global__ __launch_bounds__(256) void cvt_bf16(
    const float* __restrict__ in, unsigned short* __restrict__ out) {
  size_t i = ((size_t)blockIdx.x * 256 + threadIdx.x) * 8;
  float4 a0 = *(const float4*)&in[i];
  float4 a1 = *(const float4*)&in[i + 4];
  uint4 d;
  d.x = (unsigned)f2bf(a0.x) | ((unsigned)f2bf(a0.y) << 16);
  d.y = (unsigned)f2bf(a0.z) | ((unsigned)f2bf(a0.w) << 16);
  d.z = (unsigned)f2bf(a1.x) | ((unsigned)f2bf(a1.y) << 16);
  d.w = (unsigned)f2bf(a1.z) | ((unsigned)f2bf(a1.w) << 16);
  *(uint4*)(&out[i]) = d;
}

// ------------- convert+transpose: fp32 [R][Ccol] -> bf16 [Ccol][R] -------------
__global__ __launch_bounds__(256) void transpose_cvt(
    const float* __restrict__ in, unsigned short* __restrict__ out,
    int R, int Ccol) {
  __shared__ unsigned short tile[32][33];
  int c0 = blockIdx.x * 32, r0 = blockIdx.y * 32;
  int tx = threadIdx.x & 31, ty = threadIdx.x >> 5;  // 32 x 8
  #pragma unroll
  for (int i = 0; i < 32; i += 8)
    tile[ty + i][tx] = f2bf(in[(size_t)(r0 + ty + i) * Ccol + c0 + tx]);
  __syncthreads();
  #pragma unroll
  for (int i = 0; i < 32; i += 8)
    out[(size_t)(c0 + ty + i) * R + r0 + tx] = tile[tx][ty + i];
}

// ---- 256x256 BT-GEMM, 8 waves (2M x 4N), BK=64, double-buffered LDS.
// Stage: global_load_lds width=16, linear LDS dest, XOR-swizzled source
// (slot (r,j) holds global 16B-chunk j^(r&7)); conflict-free b128 reads.
// Prefetch of K-tile t+1 issued at top of tile t's compute (window ~3
// phases); one vmcnt(0) drain per K-tile (the __syncthreads). 4 phases
// per tile, each = {12 ds_read_b128, s_barrier, setprio+16 MFMA, s_barrier}.
__device__ __forceinline__ void stage_tile256(
    const unsigned short* __restrict__ A, const unsigned short* __restrict__ Bt,
    int K, int m0, int n0, int k0,
    unsigned short* As, unsigned short* Bs, int lane, int w) {
  const int lrow = lane >> 3;                 // 8 rows x 8 chunks per load
  const int gch = (lane & 7) ^ lrow;          // swizzled source chunk
  #pragma unroll
  for (int u = 0; u < 4; u++) {
    int g = w * 4 + u;                        // region 0..31 (8 rows each)
    int row = g * 8 + lrow;
    async_copy16(&A[(size_t)(m0 + row) * K + k0 + gch * 8], &As[g * 512]);
  }
  #pragma unroll
  for (int u = 0; u < 4; u++) {
    int g = w * 4 + u;
    int row = g * 8 + lrow;
    async_copy16(&Bt[(size_t)(n0 + row) * K + k0 + gch * 8], &Bs[g * 512]);
  }
}

__device__ __forceinline__ void gemm_bt_256(
    const unsigned short* __restrict__ A, const unsigned short* __restrict__ Bt,
    int K, int m0, int n0,
    unsigned short* AsB, unsigned short* BsB,   // each [2][256*64]
    floatx4 acc[8][4]) {
  const int t = threadIdx.x, lane = t & 63, w = t >> 6;
  const int wr = w >> 2, wc = w & 3;            // wave -> 128x64 output tile
  const int l15 = lane & 15, l4 = lane >> 4;
  const floatx4 zf = {0.f, 0.f, 0.f, 0.f};
  #pragma unroll
  for (int mi = 0; mi < 8; mi++)
    #pragma unroll
    for (int ni = 0; ni < 4; ni++) acc[mi][ni] = zf;

  const int nkt = K >> 6;
  stage_tile256(A, Bt, K, m0, n0, 0, AsB, BsB, lane, w);
  __syncthreads();                              // tile 0 staged & visible

  #pragma unroll 1
  for (int kt = 0; kt < nkt; kt++) {
    const unsigned short* Ab = AsB + (kt & 1) * 16384;
    const unsigned short* Bb = BsB + (kt & 1) * 16384;
    if (kt + 1 < nkt)                           // prefetch into other buffer
      stage_tile256(A, Bt, K, m0, n0, (kt + 1) * 64,
                    AsB + ((kt + 1) & 1) * 16384,
                    BsB + ((kt + 1) & 1) * 16384, lane, w);
    #pragma unroll
    for (int j = 0; j < 4; j++) {               // 4 phases: one C-quadrant each
      const int qm = j >> 1, qn = j & 1;
      bf16x8 af[4][2], bfr[2][2];
      #pragma unroll
      for (int mi = 0; mi < 4; mi++) {
        int row = wr * 128 + (qm * 4 + mi) * 16 + l15;
        #pragma unroll
        for (int kk = 0; kk < 2; kk++)
          af[mi][kk] = *(const bf16x8*)(
              &Ab[row * 64 + (((kk * 4 + l4) ^ (l15 & 7)) << 3)]);
      }
      #pragma unroll
      for (int ni = 0; ni < 2; ni++) {
        int row = wc * 64 + (qn * 2 + ni) * 16 + l15;
        #pragma unroll
        for (int kk = 0; kk < 2; kk++)
          bfr[ni][kk] = *(const bf16x8*)(
              &Bb[row * 64 + (((kk * 4 + l4) ^ (l15 & 7)) << 3)]);
      }
      __builtin_amdgcn_s_barrier();             // cluster waves into MFMA phase
      __builtin_amdgcn_s_setprio(1);
      #pragma unroll
      for (int kk = 0; kk < 2; kk++)
        #pragma unroll
        for (int mi = 0; mi < 4; mi++)
          #pragma unroll
          for (int ni = 0; ni < 2; ni++)
            acc[qm * 4 + mi][qn * 2 + ni] = __builtin_amdgcn_mfma_f32_16x16x32_bf16(
                af[mi][kk], bfr[ni][kk], acc[qm * 4 + mi][qn * 2 + ni], 0, 0, 0);
      __builtin_amdgcn_s_setprio(0);
      if (j < 3) __builtin_amdgcn_s_barrier();
    }
    __syncthreads();   // vmcnt(0): prefetch landed; all reads of cur done
  }
}

// ---- GEMM1: qkv = xb(bf16) @ w_qkvT(bf16) + b(fp32); Q,K [B,H,S,D], V^T [B,H,D,S]
__global__ __launch_bounds__(512, 2) void gemm_qkv(
    const unsigned short* __restrict__ X, const unsigned short* __restrict__ WT,
    const float* __restrict__ bias,
    unsigned short* __restrict__ Qo, unsigned short* __restrict__ Ko,
    unsigned short* __restrict__ Vto) {
  __shared__ unsigned short As[2][256 * 64];
  __shared__ unsigned short Bs[2][256 * 64];
  // XCD-aware swizzle (grid % 8 == 0): consecutive lg share bn -> B panel
  // (1 MiB) stays L2-resident per XCD while A streams.
  int id = blockIdx.x;
  int n8 = gridDim.x >> 3;
  int lg = (id & 7) * n8 + (id >> 3);
  int bm = lg & 31, bn = lg >> 5;               // M=8192 -> 32 m-blocks
  int m0 = bm * 256, n0 = bn * 256;
  floatx4 acc[8][4];
  gemm_bt_256(X, WT, 2048, m0, n0, As[0], Bs[0], acc);

  const int t = threadIdx.x, lane = t & 63, w = t >> 6;
  const int wr = w >> 2, wc = w & 3;
  const int l15 = lane & 15, l4 = lane >> 4;
  int which = n0 >> 11;            // 0:Q 1:K 2:V  (2048 % 256 == 0)
  int b = m0 >> 11;
  int s0 = m0 & 2047;
  float bv[4];
  #pragma unroll
  for (int ni = 0; ni < 4; ni++)
    bv[ni] = bias[n0 + wc * 64 + ni * 16 + l15];

  if (which < 2) {
    unsigned short* dst = (which == 0) ? Qo : Ko;
    #pragma unroll
    for (int ni = 0; ni < 4; ni++) {
      int cn = (n0 & 2047) + wc * 64 + ni * 16;
      int h = cn >> 7, d = (cn & 127) + l15;
      size_t base = ((size_t)(b * 16 + h)) * 2048;
      #pragma unroll
      for (int mi = 0; mi < 8; mi++) {
        #pragma unroll
        for (int r = 0; r < 4; r++) {
          int srow = s0 + wr * 128 + mi * 16 + l4 * 4 + r;
          dst[(base + srow) * 128 + d] = f2bf(acc[mi][ni][r] + bv[ni]);
        }
      }
    }
  } else {
    #pragma unroll
    for (int ni = 0; ni < 4; ni++) {
      int cn = (n0 & 2047) + wc * 64 + ni * 16;
      int h = cn >> 7, d = (cn & 127) + l15;
      #pragma unroll
      for (int mi = 0; mi < 8; mi++) {
        int sr = s0 + wr * 128 + mi * 16 + l4 * 4;   // 4 consecutive s rows
        ushort4 v;
        v.x = f2bf(acc[mi][ni][0] + bv[ni]);
        v.y = f2bf(acc[mi][ni][1] + bv[ni]);
        v.z = f2bf(acc[mi][ni][2] + bv[ni]);
        v.w = f2bf(acc[mi][ni][3] + bv[ni]);
        *(ushort4*)(&Vto[((size_t)(b * 16 + h) * 128 + d) * 2048 + sr]) = v;
      }
    }
  }
}

// ---- attn staging (512 threads): K tile [64][128] + V^T tile [128][64] via
// global_load_lds width=16; linear LDS dest, XOR-swizzled global source.
__device__ __forceinline__ void attn_stage(
    const unsigned short* __restrict__ Kb, const unsigned short* __restrict__ Vb,
    __bf16* Ksel, __bf16* Vsel, int k0, int lane, int w) {
  const int krow_in = lane >> 4, kch = lane & 15;  // K: 4 rows x 16 chunks / load
  const int vrow_in = lane >> 3, vch = lane & 7;   // V: 8 rows x 8 chunks / load
  #pragma unroll
  for (int u = 0; u < 2; u++) {
    int uk = w * 2 + u;
    int row = uk * 4 + krow_in;
    int sch = kch ^ (row & 7);
    async_copy16(&Kb[(size_t)(k0 + row) * 128 + sch * 8], Ksel + uk * 512);
  }
  #pragma unroll
  for (int u = 0; u < 2; u++) {
    int uv = w * 2 + u;
    int row = uv * 8 + vrow_in;                    // row & 7 == vrow_in
    int sch = vch ^ vrow_in;
    async_copy16(&Vb[(size_t)row * 2048 + k0 + sch * 8], Vsel + uv * 512);
  }
}

// ---- flash attention, 8-wave blocks, swapped-QK^T in-register softmax.
__global__ __launch_bounds__(512, 4) void attn(
    const unsigned short* __restrict__ Qg, const unsigned short* __restrict__ Kg,
    const unsigned short* __restrict__ Vtg, unsigned short* __restrict__ Yg) {
  const int S = 2048, Dh = 128;
  const float c1 = 0.08838834764831845f * 1.4426950408889634f;  // scale*log2e
  const float NEG_BIG = -3.0e38f;
  __shared__ __bf16 Ks[2][64 * 128];   // K tile, swizzled chunks, no pad
  __shared__ __bf16 Vs[2][128 * 64];   // V^T tile, swizzled chunks, no pad
  __shared__ __bf16 Ps[8][16 * 64];    // per-wave P [16 q][64 k], swizzled

  int wg = blockIdx.x;
  int lg = (wg & 7) * 64 + (wg >> 3);  // 512 blocks, 512%8==0 (bijective)
  int qtp = lg & 7;                    // 8 q-pair slots
  int bh = lg >> 3;
  const int t = threadIdx.x, lane = t & 63, w = t >> 6;
  const int l15 = lane & 15, l4 = lane >> 4;
  const unsigned short* Qb = Qg + (size_t)bh * S * Dh;
  const unsigned short* Kb = Kg + (size_t)bh * S * Dh;
  const unsigned short* Vb = Vtg + (size_t)bh * Dh * S;
  __bf16* Pw = Ps[w];
  int b = bh >> 4, h = bh & 15;
  const floatx4 zf = {0.f, 0.f, 0.f, 0.f};

  #pragma unroll 1
  for (int half = 0; half < 2; half++) {
    int jq = half ? qtp : (15 - qtp);  // pair long+short: 34 tiles per block
    int qb0 = jq * 128;
    int qrow_base = qb0 + w * 16;
    bf16x8 qf[4];
    #pragma unroll
    for (int kk = 0; kk < 4; kk++)
      qf[kk] = *(const bf16x8*)(
          &Qb[(size_t)(qrow_base + l15) * Dh + kk * 32 + l4 * 8]);
    floatx4 accO[8];
    #pragma unroll
    for (int nd = 0; nd < 8; nd++) accO[nd] = zf;
    float mst = NEG_BIG, lst = 0.f;    // per-lane: q = qrow_base + l15

    int ntiles = 2 * jq + 2;
    int cur = 0;
    attn_stage(Kb, Vb, Ks[0], Vs[0], 0, lane, w);
    __syncthreads();                   // vmcnt(0) drain + barrier: tile 0 ready

    #pragma unroll 1
    for (int kt = 0; kt < ntiles; kt++) {
      if (kt + 1 < ntiles)             // async prefetch into other buffer
        attn_stage(Kb, Vb, Ks[cur ^ 1], Vs[cur ^ 1], (kt + 1) * 64, lane, w);

      const __bf16* Kcur = Ks[cur];
      const __bf16* Vcur = Vs[cur];
      floatx4 sc[4];                   // sc[ni][r]: key=ni*16+l4*4+r, q=l15
      #pragma unroll
      for (int ni = 0; ni < 4; ni++) sc[ni] = zf;
      __builtin_amdgcn_s_setprio(1);
      #pragma unroll
      for (int kk = 0; kk < 4; kk++) { // swapped QK^T over D=128
        bf16x8 kf[4];
        #pragma unroll
        for (int ni = 0; ni < 4; ni++) {
          int row = ni * 16 + l15;
          kf[ni] = *(const bf16x8*)(
              &Kcur[row * 128 + (((kk * 4 + l4) ^ (l15 & 7)) << 3)]);
        }
        #pragma unroll
        for (int ni = 0; ni < 4; ni++)
          sc[ni] = __builtin_amdgcn_mfma_f32_16x16x32_bf16(kf[ni], qf[kk], sc[ni], 0, 0, 0);
      }
      __builtin_amdgcn_s_setprio(0);

      if (kt >= 2 * jq) {              // only last two tiles can mask
        int kb = kt * 64 - qb0 - w * 16 - l15;
        #pragma unroll
        for (int ni = 0; ni < 4; ni++)
          #pragma unroll
          for (int r = 0; r < 4; r++)
            if (kb + ni * 16 + l4 * 4 + r > 0) sc[ni][r] = NEG_BIG;
      }

      // row max: in-lane over 16, then across l4 (lanes sharing l15)
      float mt = fmaxf(fmaxf(fmaxf(sc[0][0], sc[0][1]), fmaxf(sc[0][2], sc[0][3])),
                       fmaxf(fmaxf(sc[1][0], sc[1][1]), fmaxf(sc[1][2], sc[1][3])));
      mt = fmaxf(mt,
           fmaxf(fmaxf(fmaxf(sc[2][0], sc[2][1]), fmaxf(sc[2][2], sc[2][3])),
                 fmaxf(fmaxf(sc[3][0], sc[3][1]), fmaxf(sc[3][2], sc[3][3]))));
      mt = fmaxf(mt, __shfl_xor(mt, 16, 64));
      mt = fmaxf(mt, __shfl_xor(mt, 32, 64));

      if (!__all(mt <= mst + 8.0f)) {  // defer-max: rescale only on growth
        float mnew = fmaxf(mst, mt);
        float alpha = exp2f((mst - mnew) * c1);
        mst = mnew;
        lst *= alpha;
        float ar[4];
        #pragma unroll
        for (int r = 0; r < 4; r++)    // alpha for accO row q=l4*4+r lives
          ar[r] = __shfl(alpha, l4 * 20 + r, 64);  // at lane l15=l4*4+r
        #pragma unroll
        for (int nd = 0; nd < 8; nd++)
          #pragma unroll
          for (int r = 0; r < 4; r++) accO[nd][r] *= ar[r];
      }

      float mc = mst * c1;
      float p[4][4];
      float rs = 0.f;
      #pragma unroll
      for (int ni = 0; ni < 4; ni++)
        #pragma unroll
        for (int r = 0; r < 4; r++) {
          p[ni][r] = exp2f(sc[ni][r] * c1 - mc);
          rs += p[ni][r];
        }
      rs += __shfl_xor(rs, 16, 64);
      rs += __shfl_xor(rs, 32, 64);
      lst += rs;

      // pack P -> per-wave LDS: block s=ni*4+l4 (keys 4s..4s+3) at
      // byte l15*128 + ((s>>1)^(l15&7))*16 + (s&1)*8
      #pragma unroll
      for (int ni = 0; ni < 4; ni++) {
        uint2 dw;
        dw.x = cvt_pk_bf16(p[ni][0], p[ni][1]);
        dw.y = cvt_pk_bf16(p[ni][2], p[ni][3]);
        int s = ni * 4 + l4;
        *(uint2*)(&Pw[l15 * 64 + (((s >> 1) ^ (l15 & 7)) << 3) + ((s & 1) << 2)]) = dw;
      }

      __builtin_amdgcn_s_setprio(1);
      #pragma unroll
      for (int kk = 0; kk < 2; kk++) {  // PV: A=P[q][k], B=V^T
        bf16x8 pf = *(const bf16x8*)(
            &Pw[l15 * 64 + (((kk * 4 + l4) ^ (l15 & 7)) << 3)]);
        #pragma unroll
        for (int nd = 0; nd < 8; nd++) {
          int row = nd * 16 + l15;
          bf16x8 vf = *(const bf16x8*)(
              &Vcur[row * 64 + (((kk * 4 + l4) ^ (l15 & 7)) << 3)]);
          accO[nd] = __builtin_amdgcn_mfma_f32_16x16x32_bf16(pf, vf, accO[nd], 0, 0, 0);
        }
      }
      __builtin_amdgcn_s_setprio(0);
      __syncthreads();   // vmcnt(0): prefetch landed; all reads of cur done
      cur ^= 1;
    }

    float invl = 1.0f / lst;
    float ivr[4];
    #pragma unroll
    for (int r = 0; r < 4; r++)
      ivr[r] = __shfl(invl, l4 * 20 + r, 64);   // state lane for q=l4*4+r
    #pragma unroll
    for (int r = 0; r < 4; r++) {
      int srow = qrow_base + l4 * 4 + r;
      size_t rowbase = ((size_t)(b * 2048 + srow)) * 2048 + h * 128;
      #pragma unroll
      for (int nd = 0; nd < 8; nd++)
        Yg[rowbase + nd * 16 + l15] = f2bf(accO[nd][r] * ivr[r]);
    }
  }
}

// ---- GEMM2: out(fp32) = y(bf16) @ w_projT(bf16) + b_proj(fp32)
__global__ __launch_bounds__(512, 2) void gemm_proj(
    const unsigned short* __restrict__ Yin, const unsigned short* __restrict__ WT,
    const float* __restrict__ bias, float* __restrict__ Og) {
  __shared__ unsigned short As[2][256 * 64];
  __shared__ unsigned short Bs[2][256 * 64];
  int id = blockIdx.x;
  int n8 = gridDim.x >> 3;
  int lg = (id & 7) * n8 + (id >> 3);
  int bm = lg & 31, bn = lg >> 5;               // M=8192 -> 32 m-blocks
  int m0 = bm * 256, n0 = bn * 256;
  floatx4 acc[8][4];
  gemm_bt_256(Yin, WT, 2048, m0, n0, As[0], Bs[0], acc);

  const int t = threadIdx.x, lane = t & 63, w = t >> 6;
  const int wr = w >> 2, wc = w & 3;
  const int l15 = lane & 15, l4 = lane >> 4;
  float bv[4];
  #pragma unroll
  for (int ni = 0; ni < 4; ni++)
    bv[ni] = bias[n0 + wc * 64 + ni * 16 + l15];
  #pragma unroll
  for (int mi = 0; mi < 8; mi++)
    #pragma unroll
    for (int ni = 0; ni < 4; ni++)
      #pragma unroll
      for (int r = 0; r < 4; r++)
        Og[(size_t)(m0 + wr * 128 + mi * 16 + l4 * 4 + r) * 2048 +
           n0 + wc * 64 + ni * 16 + l15] = acc[mi][ni][r] + bv[ni];
}

extern "C" void kernel_launch(void* const* d_in, const int* in_sizes, int n_in,
                              void* d_out, int out_size, void* d_ws, size_t ws_size,
                              hipStream_t stream) {
  const float* x      = (const float*)d_in[0]; // [4,2048,2048] fp32
  const float* w_qkv  = (const float*)d_in[1]; // [2048,6144] fp32
  const float* b_qkv  = (const float*)d_in[2]; // [6144] fp32
  const float* w_proj = (const float*)d_in[3]; // [2048,2048] fp32
  const float* b_proj = (const float*)d_in[4]; // [2048] fp32
  float* out = (float*)d_out;                  // [4,2048,2048] fp32 (64 MiB)
  char* ws = (char*)d_ws;

  // d_out doubles as mid-pipeline scratch (fully overwritten by gemm_proj):
  //   Q bf16 at d_out[0,32M), K bf16 at d_out[32M,64M)
  // ws (88 MiB peak), lifetime-shared:
  //   [0,32M):  Vt bf16 [B,H,D,S]
  //   [32,64M): Xbf bf16 (cvt_x -> gemm_qkv), then Y bf16 (attn -> gemm_proj)
  //   [64,88M): WqT bf16 [6144,2048], later WpT bf16 [2048,2048]
  unsigned short* Q   = (unsigned short*)d_out;
  unsigned short* Kt  = (unsigned short*)((char*)d_out + 33554432);
  unsigned short* Vt  = (unsigned short*)(ws);
  unsigned short* Xbf = (unsigned short*)(ws + 33554432);
  unsigned short* Y   = (unsigned short*)(ws + 33554432);
  unsigned short* WqT = (unsigned short*)(ws + 67108864);
  unsigned short* WpT = (unsigned short*)(ws + 67108864);

  cvt_bf16<<<dim3(8192), 256, 0, stream>>>(x, Xbf);                    // 16M elems
  transpose_cvt<<<dim3(192, 64), 256, 0, stream>>>(w_qkv, WqT, 2048, 6144);
  gemm_qkv<<<dim3(768), 512, 0, stream>>>(Xbf, WqT, b_qkv, Q, Kt, Vt);
  attn<<<dim3(512), 512, 0, stream>>>(Q, Kt, Vt, Y);
  transpose_cvt<<<dim3(64, 64), 256, 0, stream>>>(w_proj, WpT, 2048, 2048);
  gemm_proj<<<dim3(256), 512, 0, stream>>>(Y, WpT, b_proj, out);
}

// Round 4
// 590.022 us; speedup vs baseline: 1.1552x; 1.1552x over previous
//
#include <hip/hip_runtime.h>
#include <hip/hip_bf16.h>

typedef __bf16 bf16x8 __attribute__((ext_vector_type(8)));
typedef float floatx4 __attribute__((ext_vector_type(4)));

__device__ __forceinline__ unsigned short f2bf(float f) {
  unsigned u = __float_as_uint(f);
  u += 0x7fffu + ((u >> 16) & 1u);   // RNE; inputs finite
  return (unsigned short)(u >> 16);
}

__device__ __forceinline__ unsigned cvt_pk_bf16(float lo, float hi) {
  unsigned r;
  asm("v_cvt_pk_bf16_f32 %0, %1, %2" : "=v"(r) : "v"(lo), "v"(hi));
  return r;   // r.lo16 = bf16(lo), r.hi16 = bf16(hi)
}

__device__ __forceinline__ void async_copy16(const void* g, void* l) {
  __builtin_amdgcn_global_load_lds(
      (const __attribute__((address_space(1))) void*)g,
      (__attribute__((address_space(3))) void*)l, 16, 0, 0);
}

// ------------- elementwise fp32 -> bf16 (8 elems/thread) -------------
__global__ __launch_bounds__(256) void cvt_bf16(
    const float* __restrict__ in, unsigned short* __restrict__ out) {
  size_t i = ((size_t)blockIdx.x * 256 + threadIdx.x) * 8;
  float4 a0 = *(const float4*)&in[i];
  float4 a1 = *(const float4*)&in[i + 4];
  uint4 d;
  d.x = (unsigned)f2bf(a0.x) | ((unsigned)f2bf(a0.y) << 16);
  d.y = (unsigned)f2bf(a0.z) | ((unsigned)f2bf(a0.w) << 16);
  d.z = (unsigned)f2bf(a1.x) | ((unsigned)f2bf(a1.y) << 16);
  d.w = (unsigned)f2bf(a1.z) | ((unsigned)f2bf(a1.w) << 16);
  *(uint4*)(&out[i]) = d;
}

// ------------- convert+transpose: fp32 [R][Ccol] -> bf16 [Ccol][R] -------------
__global__ __launch_bounds__(256) void transpose_cvt(
    const float* __restrict__ in, unsigned short* __restrict__ out,
    int R, int Ccol) {
  __shared__ unsigned short tile[32][33];
  int c0 = blockIdx.x * 32, r0 = blockIdx.y * 32;
  int tx = threadIdx.x & 31, ty = threadIdx.x >> 5;  // 32 x 8
  #pragma unroll
  for (int i = 0; i < 32; i += 8)
    tile[ty + i][tx] = f2bf(in[(size_t)(r0 + ty + i) * Ccol + c0 + tx]);
  __syncthreads();
  #pragma unroll
  for (int i = 0; i < 32; i += 8)
    out[(size_t)(c0 + ty + i) * R + r0 + tx] = tile[tx][ty + i];
}

// ---- 256x256 BT-GEMM, 8 waves (2M x 4N), BK=64, double-buffered LDS,
// COUNTED-vmcnt pipeline (never drains to 0 in the main loop).
// Stage: global_load_lds width=16, linear LDS dest, XOR-swizzled source
// (slot (r,j) holds global 16B-chunk j^(r&7)); conflict-free b128 reads.
// Tile kt+1 staged as 4 chunks of 2 loads/thread: chunk0 at iteration top,
// chunks 1-3 inside phases 0-2. At top: s_waitcnt vmcnt(2) confirms tile kt
// (only the 2 just-issued loads outstanding) -> loads stay in flight across
// all barriers. Raw s_barrier only (no implicit vmcnt drain).
__device__ __forceinline__ void stage_chunk256(
    const unsigned short* __restrict__ A, const unsigned short* __restrict__ Bt,
    int K, int m0, int n0, int k0,
    unsigned short* As, unsigned short* Bs, int lane, int w, int j) {
  const int lrow = lane >> 3;                 // 8 rows x 8 chunks per load
  const int gch = (lane & 7) ^ lrow;          // swizzled source chunk
  if (j < 2) {
    #pragma unroll
    for (int u = 2 * j; u < 2 * j + 2; u++) {
      int g = w * 4 + u;                      // A region 0..31 (8 rows each)
      int row = g * 8 + lrow;
      async_copy16(&A[(size_t)(m0 + row) * K + k0 + gch * 8], &As[g * 512]);
    }
  } else {
    #pragma unroll
    for (int u = 2 * (j - 2); u < 2 * (j - 2) + 2; u++) {
      int g = w * 4 + u;
      int row = g * 8 + lrow;
      async_copy16(&Bt[(size_t)(n0 + row) * K + k0 + gch * 8], &Bs[g * 512]);
    }
  }
}

__device__ __forceinline__ void gemm_bt_256(
    const unsigned short* __restrict__ A, const unsigned short* __restrict__ Bt,
    int K, int m0, int n0,
    unsigned short* AsB, unsigned short* BsB,   // each [2][256*64]
    floatx4 acc[8][4]) {
  const int t = threadIdx.x, lane = t & 63, w = t >> 6;
  const int wr = w >> 2, wc = w & 3;            // wave -> 128x64 output tile
  const int l15 = lane & 15, l4 = lane >> 4;
  const floatx4 zf = {0.f, 0.f, 0.f, 0.f};
  #pragma unroll
  for (int mi = 0; mi < 8; mi++)
    #pragma unroll
    for (int ni = 0; ni < 4; ni++) acc[mi][ni] = zf;

  const int nkt = K >> 6;
  #pragma unroll
  for (int j = 0; j < 4; j++)                   // prologue: tile 0 (8 loads)
    stage_chunk256(A, Bt, K, m0, n0, 0, AsB, BsB, lane, w, j);

  #pragma unroll 1
  for (int kt = 0; kt < nkt; kt++) {
    const unsigned short* Ab = AsB + (kt & 1) * 16384;
    const unsigned short* Bb = BsB + (kt & 1) * 16384;
    unsigned short* An = AsB + ((kt + 1) & 1) * 16384;
    unsigned short* Bn = BsB + ((kt + 1) & 1) * 16384;
    const bool pf = (kt + 1 < nkt);
    // --- iteration top: issue chunk0 of kt+1, then counted wait for tile kt
    if (pf) {
      stage_chunk256(A, Bt, K, m0, n0, (kt + 1) * 64, An, Bn, lane, w, 0);
      asm volatile("s_waitcnt vmcnt(2)" ::: "memory");  // tile kt confirmed
    } else {
      asm volatile("s_waitcnt vmcnt(0)" ::: "memory");  // last tile: all done
    }
    __builtin_amdgcn_s_barrier();               // all waves confirmed tile kt
    #pragma unroll
    for (int j = 0; j < 4; j++) {               // 4 phases: one C-quadrant each
      const int qm = j >> 1, qn = j & 1;
      bf16x8 af[4][2], bfr[2][2];
      #pragma unroll
      for (int mi = 0; mi < 4; mi++) {
        int row = wr * 128 + (qm * 4 + mi) * 16 + l15;
        #pragma unroll
        for (int kk = 0; kk < 2; kk++)
          af[mi][kk] = *(const bf16x8*)(
              &Ab[row * 64 + (((kk * 4 + l4) ^ (l15 & 7)) << 3)]);
      }
      #pragma unroll
      for (int ni = 0; ni < 2; ni++) {
        int row = wc * 64 + (qn * 2 + ni) * 16 + l15;
        #pragma unroll
        for (int kk = 0; kk < 2; kk++)
          bfr[ni][kk] = *(const bf16x8*)(
              &Bb[row * 64 + (((kk * 4 + l4) ^ (l15 & 7)) << 3)]);
      }
      if (j < 3 && pf)                          // in-flight prefetch chunk j+1
        stage_chunk256(A, Bt, K, m0, n0, (kt + 1) * 64, An, Bn, lane, w, j + 1);
      __builtin_amdgcn_s_barrier();             // cluster waves into MFMA phase
      __builtin_amdgcn_s_setprio(1);
      #pragma unroll
      for (int kk = 0; kk < 2; kk++)
        #pragma unroll
        for (int mi = 0; mi < 4; mi++)
          #pragma unroll
          for (int ni = 0; ni < 2; ni++)
            acc[qm * 4 + mi][qn * 2 + ni] = __builtin_amdgcn_mfma_f32_16x16x32_bf16(
                af[mi][kk], bfr[ni][kk], acc[qm * 4 + mi][qn * 2 + ni], 0, 0, 0);
      __builtin_amdgcn_s_setprio(0);
      if (j < 3) __builtin_amdgcn_s_barrier();
    }
  }
  __builtin_amdgcn_s_barrier();                 // epilogue reads acc only; sync tail
}

// ---- GEMM1: qkv = xb(bf16) @ w_qkvT(bf16) + b(fp32); Q,K [B,H,S,D], V^T [B,H,D,S]
__global__ __launch_bounds__(512, 2) void gemm_qkv(
    const unsigned short* __restrict__ X, const unsigned short* __restrict__ WT,
    const float* __restrict__ bias,
    unsigned short* __restrict__ Qo, unsigned short* __restrict__ Ko,
    unsigned short* __restrict__ Vto) {
  __shared__ unsigned short As[2][256 * 64];
  __shared__ unsigned short Bs[2][256 * 64];
  // n-fastest ordering (round-2 measured winner: A panel L2-resident/XCD)
  int lg = blockIdx.x;
  int bn = lg % 24, bm = lg / 24;               // N=6144 -> 24, M=8192 -> 32
  int m0 = bm * 256, n0 = bn * 256;
  floatx4 acc[8][4];
  gemm_bt_256(X, WT, 2048, m0, n0, As[0], Bs[0], acc);

  const int t = threadIdx.x, lane = t & 63, w = t >> 6;
  const int wr = w >> 2, wc = w & 3;
  const int l15 = lane & 15, l4 = lane >> 4;
  int which = n0 >> 11;            // 0:Q 1:K 2:V  (2048 % 256 == 0)
  int b = m0 >> 11;
  int s0 = m0 & 2047;
  float bv[4];
  #pragma unroll
  for (int ni = 0; ni < 4; ni++)
    bv[ni] = bias[n0 + wc * 64 + ni * 16 + l15];

  if (which < 2) {
    unsigned short* dst = (which == 0) ? Qo : Ko;
    #pragma unroll
    for (int ni = 0; ni < 4; ni++) {
      int cn = (n0 & 2047) + wc * 64 + ni * 16;
      int h = cn >> 7, d = (cn & 127) + l15;
      size_t base = ((size_t)(b * 16 + h)) * 2048;
      #pragma unroll
      for (int mi = 0; mi < 8; mi++) {
        #pragma unroll
        for (int r = 0; r < 4; r++) {
          int srow = s0 + wr * 128 + mi * 16 + l4 * 4 + r;
          dst[(base + srow) * 128 + d] = f2bf(acc[mi][ni][r] + bv[ni]);
        }
      }
    }
  } else {
    #pragma unroll
    for (int ni = 0; ni < 4; ni++) {
      int cn = (n0 & 2047) + wc * 64 + ni * 16;
      int h = cn >> 7, d = (cn & 127) + l15;
      #pragma unroll
      for (int mi = 0; mi < 8; mi++) {
        int sr = s0 + wr * 128 + mi * 16 + l4 * 4;   // 4 consecutive s rows
        ushort4 v;
        v.x = f2bf(acc[mi][ni][0] + bv[ni]);
        v.y = f2bf(acc[mi][ni][1] + bv[ni]);
        v.z = f2bf(acc[mi][ni][2] + bv[ni]);
        v.w = f2bf(acc[mi][ni][3] + bv[ni]);
        *(ushort4*)(&Vto[((size_t)(b * 16 + h) * 128 + d) * 2048 + sr]) = v;
      }
    }
  }
}

// ---- attn staging (512 threads): K tile [64][128] + V^T tile [128][64] via
// global_load_lds width=16; linear LDS dest, XOR-swizzled global source.
__device__ __forceinline__ void attn_stage(
    const unsigned short* __restrict__ Kb, const unsigned short* __restrict__ Vb,
    __bf16* Ksel, __bf16* Vsel, int k0, int lane, int w) {
  const int krow_in = lane >> 4, kch = lane & 15;  // K: 4 rows x 16 chunks / load
  const int vrow_in = lane >> 3, vch = lane & 7;   // V: 8 rows x 8 chunks / load
  #pragma unroll
  for (int u = 0; u < 2; u++) {
    int uk = w * 2 + u;
    int row = uk * 4 + krow_in;
    int sch = kch ^ (row & 7);
    async_copy16(&Kb[(size_t)(k0 + row) * 128 + sch * 8], Ksel + uk * 512);
  }
  #pragma unroll
  for (int u = 0; u < 2; u++) {
    int uv = w * 2 + u;
    int row = uv * 8 + vrow_in;                    // row & 7 == vrow_in
    int sch = vch ^ vrow_in;
    async_copy16(&Vb[(size_t)row * 2048 + k0 + sch * 8], Vsel + uv * 512);
  }
}

// ---- flash attention, 8-wave blocks, swapped-QK^T in-register softmax.
__global__ __launch_bounds__(512, 4) void attn(
    const unsigned short* __restrict__ Qg, const unsigned short* __restrict__ Kg,
    const unsigned short* __restrict__ Vtg, unsigned short* __restrict__ Yg) {
  const int S = 2048, Dh = 128;
  const float c1 = 0.08838834764831845f * 1.4426950408889634f;  // scale*log2e
  const float NEG_BIG = -3.0e38f;
  __shared__ __bf16 Ks[2][64 * 128];   // K tile, swizzled chunks, no pad
  __shared__ __bf16 Vs[2][128 * 64];   // V^T tile, swizzled chunks, no pad
  __shared__ __bf16 Ps[8][16 * 64];    // per-wave P [16 q][64 k], swizzled

  int wg = blockIdx.x;
  int lg = (wg & 7) * 64 + (wg >> 3);  // 512 blocks, 512%8==0 (bijective)
  int qtp = lg & 7;                    // 8 q-pair slots
  int bh = lg >> 3;
  const int t = threadIdx.x, lane = t & 63, w = t >> 6;
  const int l15 = lane & 15, l4 = lane >> 4;
  const unsigned short* Qb = Qg + (size_t)bh * S * Dh;
  const unsigned short* Kb = Kg + (size_t)bh * S * Dh;
  const unsigned short* Vb = Vtg + (size_t)bh * Dh * S;
  __bf16* Pw = Ps[w];
  int b = bh >> 4, h = bh & 15;
  const floatx4 zf = {0.f, 0.f, 0.f, 0.f};

  #pragma unroll 1
  for (int half = 0; half < 2; half++) {
    int jq = half ? qtp : (15 - qtp);  // pair long+short: 34 tiles per block
    int qb0 = jq * 128;
    int qrow_base = qb0 + w * 16;
    bf16x8 qf[4];
    #pragma unroll
    for (int kk = 0; kk < 4; kk++)
      qf[kk] = *(const bf16x8*)(
          &Qb[(size_t)(qrow_base + l15) * Dh + kk * 32 + l4 * 8]);
    floatx4 accO[8];
    #pragma unroll
    for (int nd = 0; nd < 8; nd++) accO[nd] = zf;
    float mst = NEG_BIG, lst = 0.f;    // per-lane: q = qrow_base + l15

    int ntiles = 2 * jq + 2;
    int cur = 0;
    attn_stage(Kb, Vb, Ks[0], Vs[0], 0, lane, w);
    __syncthreads();                   // vmcnt(0) drain + barrier: tile 0 ready

    #pragma unroll 1
    for (int kt = 0; kt < ntiles; kt++) {
      if (kt + 1 < ntiles)             // async prefetch into other buffer
        attn_stage(Kb, Vb, Ks[cur ^ 1], Vs[cur ^ 1], (kt + 1) * 64, lane, w);

      const __bf16* Kcur = Ks[cur];
      const __bf16* Vcur = Vs[cur];
      floatx4 sc[4];                   // sc[ni][r]: key=ni*16+l4*4+r, q=l15
      #pragma unroll
      for (int ni = 0; ni < 4; ni++) sc[ni] = zf;
      __builtin_amdgcn_s_setprio(1);
      #pragma unroll
      for (int kk = 0; kk < 4; kk++) { // swapped QK^T over D=128
        bf16x8 kf[4];
        #pragma unroll
        for (int ni = 0; ni < 4; ni++) {
          int row = ni * 16 + l15;
          kf[ni] = *(const bf16x8*)(
              &Kcur[row * 128 + (((kk * 4 + l4) ^ (l15 & 7)) << 3)]);
        }
        #pragma unroll
        for (int ni = 0; ni < 4; ni++)
          sc[ni] = __builtin_amdgcn_mfma_f32_16x16x32_bf16(kf[ni], qf[kk], sc[ni], 0, 0, 0);
      }
      __builtin_amdgcn_s_setprio(0);

      if (kt >= 2 * jq) {              // only last two tiles can mask
        int kb = kt * 64 - qb0 - w * 16 - l15;
        #pragma unroll
        for (int ni = 0; ni < 4; ni++)
          #pragma unroll
          for (int r = 0; r < 4; r++)
            if (kb + ni * 16 + l4 * 4 + r > 0) sc[ni][r] = NEG_BIG;
      }

      // row max: in-lane over 16, then across l4 (lanes sharing l15)
      float mt = fmaxf(fmaxf(fmaxf(sc[0][0], sc[0][1]), fmaxf(sc[0][2], sc[0][3])),
                       fmaxf(fmaxf(sc[1][0], sc[1][1]), fmaxf(sc[1][2], sc[1][3])));
      mt = fmaxf(mt,
           fmaxf(fmaxf(fmaxf(sc[2][0], sc[2][1]), fmaxf(sc[2][2], sc[2][3])),
                 fmaxf(fmaxf(sc[3][0], sc[3][1]), fmaxf(sc[3][2], sc[3][3]))));
      mt = fmaxf(mt, __shfl_xor(mt, 16, 64));
      mt = fmaxf(mt, __shfl_xor(mt, 32, 64));

      if (!__all(mt <= mst + 8.0f)) {  // defer-max: rescale only on growth
        float mnew = fmaxf(mst, mt);
        float alpha = exp2f((mst - mnew) * c1);
        mst = mnew;
        lst *= alpha;
        float ar[4];
        #pragma unroll
        for (int r = 0; r < 4; r++)    // alpha for accO row q=l4*4+r lives
          ar[r] = __shfl(alpha, l4 * 20 + r, 64);  // at lane l15=l4*4+r
        #pragma unroll
        for (int nd = 0; nd < 8; nd++)
          #pragma unroll
          for (int r = 0; r < 4; r++) accO[nd][r] *= ar[r];
      }

      float mc = mst * c1;
      float p[4][4];
      float rs = 0.f;
      #pragma unroll
      for (int ni = 0; ni < 4; ni++)
        #pragma unroll
        for (int r = 0; r < 4; r++) {
          p[ni][r] = exp2f(sc[ni][r] * c1 - mc);
          rs += p[ni][r];
        }
      rs += __shfl_xor(rs, 16, 64);
      rs += __shfl_xor(rs, 32, 64);
      lst += rs;

      // pack P -> per-wave LDS: block s=ni*4+l4 (keys 4s..4s+3) at
      // byte l15*128 + ((s>>1)^(l15&7))*16 + (s&1)*8
      #pragma unroll
      for (int ni = 0; ni < 4; ni++) {
        uint2 dw;
        dw.x = cvt_pk_bf16(p[ni][0], p[ni][1]);
        dw.y = cvt_pk_bf16(p[ni][2], p[ni][3]);
        int s = ni * 4 + l4;
        *(uint2*)(&Pw[l15 * 64 + (((s >> 1) ^ (l15 & 7)) << 3) + ((s & 1) << 2)]) = dw;
      }

      __builtin_amdgcn_s_setprio(1);
      #pragma unroll
      for (int kk = 0; kk < 2; kk++) {  // PV: A=P[q][k], B=V^T
        bf16x8 pf = *(const bf16x8*)(
            &Pw[l15 * 64 + (((kk * 4 + l4) ^ (l15 & 7)) << 3)]);
        #pragma unroll
        for (int nd = 0; nd < 8; nd++) {
          int row = nd * 16 + l15;
          bf16x8 vf = *(const bf16x8*)(
              &Vcur[row * 64 + (((kk * 4 + l4) ^ (l15 & 7)) << 3)]);
          accO[nd] = __builtin_amdgcn_mfma_f32_16x16x32_bf16(pf, vf, accO[nd], 0, 0, 0);
        }
      }
      __builtin_amdgcn_s_setprio(0);
      __syncthreads();   // vmcnt(0): prefetch landed; all reads of cur done
      cur ^= 1;
    }

    float invl = 1.0f / lst;
    float ivr[4];
    #pragma unroll
    for (int r = 0; r < 4; r++)
      ivr[r] = __shfl(invl, l4 * 20 + r, 64);   // state lane for q=l4*4+r
    #pragma unroll
    for (int r = 0; r < 4; r++) {
      int srow = qrow_base + l4 * 4 + r;
      size_t rowbase = ((size_t)(b * 2048 + srow)) * 2048 + h * 128;
      #pragma unroll
      for (int nd = 0; nd < 8; nd++)
        Yg[rowbase + nd * 16 + l15] = f2bf(accO[nd][r] * ivr[r]);
    }
  }
}

// ---- GEMM2: out(fp32) = y(bf16) @ w_projT(bf16) + b_proj(fp32)
__global__ __launch_bounds__(512, 2) void gemm_proj(
    const unsigned short* __restrict__ Yin, const unsigned short* __restrict__ WT,
    const float* __restrict__ bias, float* __restrict__ Og) {
  __shared__ unsigned short As[2][256 * 64];
  __shared__ unsigned short Bs[2][256 * 64];
  int lg = blockIdx.x;
  int bn = lg % 8, bm = lg / 8;                 // N=2048 -> 8, M=8192 -> 32
  int m0 = bm * 256, n0 = bn * 256;
  floatx4 acc[8][4];
  gemm_bt_256(Yin, WT, 2048, m0, n0, As[0], Bs[0], acc);

  const int t = threadIdx.x, lane = t & 63, w = t >> 6;
  const int wr = w >> 2, wc = w & 3;
  const int l15 = lane & 15, l4 = lane >> 4;
  float bv[4];
  #pragma unroll
  for (int ni = 0; ni < 4; ni++)
    bv[ni] = bias[n0 + wc * 64 + ni * 16 + l15];
  #pragma unroll
  for (int mi = 0; mi < 8; mi++)
    #pragma unroll
    for (int ni = 0; ni < 4; ni++)
      #pragma unroll
      for (int r = 0; r < 4; r++)
        Og[(size_t)(m0 + wr * 128 + mi * 16 + l4 * 4 + r) * 2048 +
           n0 + wc * 64 + ni * 16 + l15] = acc[mi][ni][r] + bv[ni];
}

extern "C" void kernel_launch(void* const* d_in, const int* in_sizes, int n_in,
                              void* d_out, int out_size, void* d_ws, size_t ws_size,
                              hipStream_t stream) {
  const float* x      = (const float*)d_in[0]; // [4,2048,2048] fp32
  const float* w_qkv  = (const float*)d_in[1]; // [2048,6144] fp32
  const float* b_qkv  = (const float*)d_in[2]; // [6144] fp32
  const float* w_proj = (const float*)d_in[3]; // [2048,2048] fp32
  const float* b_proj = (const float*)d_in[4]; // [2048] fp32
  float* out = (float*)d_out;                  // [4,2048,2048] fp32 (64 MiB)
  char* ws = (char*)d_ws;

  // d_out doubles as mid-pipeline scratch (fully overwritten by gemm_proj):
  //   Q bf16 at d_out[0,32M), K bf16 at d_out[32M,64M)
  // ws (88 MiB peak), lifetime-shared:
  //   [0,32M):  Vt bf16 [B,H,D,S]
  //   [32,64M): Xbf bf16 (cvt_x -> gemm_qkv), then Y bf16 (attn -> gemm_proj)
  //   [64,88M): WqT bf16 [6144,2048], later WpT bf16 [2048,2048]
  unsigned short* Q   = (unsigned short*)d_out;
  unsigned short* Kt  = (unsigned short*)((char*)d_out + 33554432);
  unsigned short* Vt  = (unsigned short*)(ws);
  unsigned short* Xbf = (unsigned short*)(ws + 33554432);
  unsigned short* Y   = (unsigned short*)(ws + 33554432);
  unsigned short* WqT = (unsigned short*)(ws + 67108864);
  unsigned short* WpT = (unsigned short*)(ws + 67108864);

  cvt_bf16<<<dim3(8192), 256, 0, stream>>>(x, Xbf);                    // 16M elems
  transpose_cvt<<<dim3(192, 64), 256, 0, stream>>>(w_qkv, WqT, 2048, 6144);
  gemm_qkv<<<dim3(768), 512, 0, stream>>>(Xbf, WqT, b_qkv, Q, Kt, Vt);
  attn<<<dim3(512), 512, 0, stream>>>(Q, Kt, Vt, Y);
  transpose_cvt<<<dim3(64, 64), 256, 0, stream>>>(w_proj, WpT, 2048, 2048);
  gemm_proj<<<dim3(256), 512, 0, stream>>>(Y, WpT, b_proj, out);
}

// Round 5
// 569.002 us; speedup vs baseline: 1.1978x; 1.0369x over previous
//
#include <hip/hip_runtime.h>
#include <hip/hip_bf16.h>

typedef __bf16 bf16x8 __attribute__((ext_vector_type(8)));
typedef float floatx4 __attribute__((ext_vector_type(4)));

__device__ __forceinline__ unsigned short f2bf(float f) {
  unsigned u = __float_as_uint(f);
  u += 0x7fffu + ((u >> 16) & 1u);   // RNE; inputs finite
  return (unsigned short)(u >> 16);
}

__device__ __forceinline__ unsigned cvt_pk_bf16(float lo, float hi) {
  unsigned r;
  asm("v_cvt_pk_bf16_f32 %0, %1, %2" : "=v"(r) : "v"(lo), "v"(hi));
  return r;   // r.lo16 = bf16(lo), r.hi16 = bf16(hi)
}

__device__ __forceinline__ void async_copy16(const void* g, void* l) {
  __builtin_amdgcn_global_load_lds(
      (const __attribute__((address_space(1))) void*)g,
      (__attribute__((address_space(3))) void*)l, 16, 0, 0);
}

// ------------- elementwise fp32 -> bf16 (8 elems/thread) -------------
__global__ __launch_bounds__(256) void cvt_bf16(
    const float* __restrict__ in, unsigned short* __restrict__ out) {
  size_t i = ((size_t)blockIdx.x * 256 + threadIdx.x) * 8;
  float4 a0 = *(const float4*)&in[i];
  float4 a1 = *(const float4*)&in[i + 4];
  uint4 d;
  d.x = (unsigned)f2bf(a0.x) | ((unsigned)f2bf(a0.y) << 16);
  d.y = (unsigned)f2bf(a0.z) | ((unsigned)f2bf(a0.w) << 16);
  d.z = (unsigned)f2bf(a1.x) | ((unsigned)f2bf(a1.y) << 16);
  d.w = (unsigned)f2bf(a1.z) | ((unsigned)f2bf(a1.w) << 16);
  *(uint4*)(&out[i]) = d;
}

// ------------- convert+transpose: fp32 [R][Ccol] -> bf16 [Ccol][R] -------------
__global__ __launch_bounds__(256) void transpose_cvt(
    const float* __restrict__ in, unsigned short* __restrict__ out,
    int R, int Ccol) {
  __shared__ unsigned short tile[32][33];
  int c0 = blockIdx.x * 32, r0 = blockIdx.y * 32;
  int tx = threadIdx.x & 31, ty = threadIdx.x >> 5;  // 32 x 8
  #pragma unroll
  for (int i = 0; i < 32; i += 8)
    tile[ty + i][tx] = f2bf(in[(size_t)(r0 + ty + i) * Ccol + c0 + tx]);
  __syncthreads();
  #pragma unroll
  for (int i = 0; i < 32; i += 8)
    out[(size_t)(c0 + ty + i) * R + r0 + tx] = tile[tx][ty + i];
}

// ---- 256x256 BT-GEMM, 8 waves (2M x 4N), BK=64, double-buffered LDS,
// counted-vmcnt pipeline, 2 phases per K-tile split by K-half (kk).
// Each phase reads its fragments from LDS exactly ONCE (af[8]+bfr[4] =
// 12 b128/wave) and fires 32 independent MFMAs -> LDS traffic halved vs
// the quadrant split (which re-read A and B 2x). 5 barriers/K-tile.
// Stage: global_load_lds width=16, linear LDS dest, XOR-swizzled source
// (slot (r,j) holds global 16B-chunk j^(r&7)); conflict-free b128 reads.
// A-rows of tile kt+1 staged at iteration top (then vmcnt(4) confirms
// tile kt: exactly the 8 oldest), B-rows staged inside phase 0; loads
// stay in flight across barriers, vmcnt never drains to 0 mid-loop.
__device__ __forceinline__ void stage_rows256(
    const unsigned short* __restrict__ P, int K, int r0, int k0,
    unsigned short* Ls, int lane, int w) {
  const int lrow = lane >> 3;                 // 8 rows x 8 chunks per load
  const int gch = (lane & 7) ^ lrow;          // swizzled source chunk
  #pragma unroll
  for (int u = 0; u < 4; u++) {
    int g = w * 4 + u;                        // region 0..31 (8 rows each)
    int row = g * 8 + lrow;
    async_copy16(&P[(size_t)(r0 + row) * K + k0 + gch * 8], &Ls[g * 512]);
  }
}

__device__ __forceinline__ void gemm_bt_256(
    const unsigned short* __restrict__ A, const unsigned short* __restrict__ Bt,
    int K, int m0, int n0,
    unsigned short* AsB, unsigned short* BsB,   // each [2][256*64]
    floatx4 acc[8][4]) {
  const int t = threadIdx.x, lane = t & 63, w = t >> 6;
  const int wr = w >> 2, wc = w & 3;            // wave -> 128x64 output tile
  const int l15 = lane & 15, l4 = lane >> 4;
  const floatx4 zf = {0.f, 0.f, 0.f, 0.f};
  #pragma unroll
  for (int mi = 0; mi < 8; mi++)
    #pragma unroll
    for (int ni = 0; ni < 4; ni++) acc[mi][ni] = zf;

  const int nkt = K >> 6;
  stage_rows256(A, K, m0, 0, AsB, lane, w);     // prologue: tile 0 (8 loads)
  stage_rows256(Bt, K, n0, 0, BsB, lane, w);

  #pragma unroll 1
  for (int kt = 0; kt < nkt; kt++) {
    const unsigned short* Ab = AsB + (kt & 1) * 16384;
    const unsigned short* Bb = BsB + (kt & 1) * 16384;
    unsigned short* An = AsB + ((kt + 1) & 1) * 16384;
    unsigned short* Bn = BsB + ((kt + 1) & 1) * 16384;
    const bool pf = (kt + 1 < nkt);
    // --- iteration top: issue A-stage of kt+1, counted wait for tile kt
    if (pf) {
      stage_rows256(A, K, m0, (kt + 1) * 64, An, lane, w);
      asm volatile("s_waitcnt vmcnt(4)" ::: "memory");  // tile kt confirmed
    } else {
      asm volatile("s_waitcnt vmcnt(0)" ::: "memory");  // last tile: all done
    }
    __builtin_amdgcn_s_barrier();               // every wave confirmed tile kt
    #pragma unroll
    for (int kk = 0; kk < 2; kk++) {            // 2 phases: one K-half each
      bf16x8 af[8], bfr[4];
      #pragma unroll
      for (int mi = 0; mi < 8; mi++) {
        int row = wr * 128 + mi * 16 + l15;
        af[mi] = *(const bf16x8*)(
            &Ab[row * 64 + (((kk * 4 + l4) ^ (l15 & 7)) << 3)]);
      }
      #pragma unroll
      for (int ni = 0; ni < 4; ni++) {
        int row = wc * 64 + ni * 16 + l15;
        bfr[ni] = *(const bf16x8*)(
            &Bb[row * 64 + (((kk * 4 + l4) ^ (l15 & 7)) << 3)]);
      }
      if (kk == 0 && pf)                        // B-stage of kt+1, in flight
        stage_rows256(Bt, K, n0, (kt + 1) * 64, Bn, lane, w);
      __builtin_amdgcn_s_barrier();             // cluster waves into MFMA phase
      __builtin_amdgcn_s_setprio(1);
      #pragma unroll
      for (int mi = 0; mi < 8; mi++)
        #pragma unroll
        for (int ni = 0; ni < 4; ni++)
          acc[mi][ni] = __builtin_amdgcn_mfma_f32_16x16x32_bf16(
              af[mi], bfr[ni], acc[mi][ni], 0, 0, 0);
      __builtin_amdgcn_s_setprio(0);
      __builtin_amdgcn_s_barrier();
    }
  }
}

// ---- GEMM1: qkv = xb(bf16) @ w_qkvT(bf16) + b(fp32); Q,K [B,H,S,D], V^T [B,H,D,S]
__global__ __launch_bounds__(512, 2) void gemm_qkv(
    const unsigned short* __restrict__ X, const unsigned short* __restrict__ WT,
    const float* __restrict__ bias,
    unsigned short* __restrict__ Qo, unsigned short* __restrict__ Ko,
    unsigned short* __restrict__ Vto) {
  __shared__ unsigned short As[2][256 * 64];
  __shared__ unsigned short Bs[2][256 * 64];
  // n-fastest ordering (round-2 measured winner: A panel L2-resident/XCD)
  int lg = blockIdx.x;
  int bn = lg % 24, bm = lg / 24;               // N=6144 -> 24, M=8192 -> 32
  int m0 = bm * 256, n0 = bn * 256;
  floatx4 acc[8][4];
  gemm_bt_256(X, WT, 2048, m0, n0, As[0], Bs[0], acc);

  const int t = threadIdx.x, lane = t & 63, w = t >> 6;
  const int wr = w >> 2, wc = w & 3;
  const int l15 = lane & 15, l4 = lane >> 4;
  int which = n0 >> 11;            // 0:Q 1:K 2:V  (2048 % 256 == 0)
  int b = m0 >> 11;
  int s0 = m0 & 2047;
  float bv[4];
  #pragma unroll
  for (int ni = 0; ni < 4; ni++)
    bv[ni] = bias[n0 + wc * 64 + ni * 16 + l15];

  if (which < 2) {
    unsigned short* dst = (which == 0) ? Qo : Ko;
    #pragma unroll
    for (int ni = 0; ni < 4; ni++) {
      int cn = (n0 & 2047) + wc * 64 + ni * 16;
      int h = cn >> 7, d = (cn & 127) + l15;
      size_t base = ((size_t)(b * 16 + h)) * 2048;
      #pragma unroll
      for (int mi = 0; mi < 8; mi++) {
        #pragma unroll
        for (int r = 0; r < 4; r++) {
          int srow = s0 + wr * 128 + mi * 16 + l4 * 4 + r;
          dst[(base + srow) * 128 + d] = f2bf(acc[mi][ni][r] + bv[ni]);
        }
      }
    }
  } else {
    #pragma unroll
    for (int ni = 0; ni < 4; ni++) {
      int cn = (n0 & 2047) + wc * 64 + ni * 16;
      int h = cn >> 7, d = (cn & 127) + l15;
      #pragma unroll
      for (int mi = 0; mi < 8; mi++) {
        int sr = s0 + wr * 128 + mi * 16 + l4 * 4;   // 4 consecutive s rows
        ushort4 v;
        v.x = f2bf(acc[mi][ni][0] + bv[ni]);
        v.y = f2bf(acc[mi][ni][1] + bv[ni]);
        v.z = f2bf(acc[mi][ni][2] + bv[ni]);
        v.w = f2bf(acc[mi][ni][3] + bv[ni]);
        *(ushort4*)(&Vto[((size_t)(b * 16 + h) * 128 + d) * 2048 + sr]) = v;
      }
    }
  }
}

// ---- attn staging (512 threads): K tile [64][128] + V^T tile [128][64] via
// global_load_lds width=16; linear LDS dest, XOR-swizzled global source.
__device__ __forceinline__ void attn_stage(
    const unsigned short* __restrict__ Kb, const unsigned short* __restrict__ Vb,
    __bf16* Ksel, __bf16* Vsel, int k0, int lane, int w) {
  const int krow_in = lane >> 4, kch = lane & 15;  // K: 4 rows x 16 chunks / load
  const int vrow_in = lane >> 3, vch = lane & 7;   // V: 8 rows x 8 chunks / load
  #pragma unroll
  for (int u = 0; u < 2; u++) {
    int uk = w * 2 + u;
    int row = uk * 4 + krow_in;
    int sch = kch ^ (row & 7);
    async_copy16(&Kb[(size_t)(k0 + row) * 128 + sch * 8], Ksel + uk * 512);
  }
  #pragma unroll
  for (int u = 0; u < 2; u++) {
    int uv = w * 2 + u;
    int row = uv * 8 + vrow_in;                    // row & 7 == vrow_in
    int sch = vch ^ vrow_in;
    async_copy16(&Vb[(size_t)row * 2048 + k0 + sch * 8], Vsel + uv * 512);
  }
}

// ---- flash attention, 8-wave blocks, swapped-QK^T in-register softmax.
__global__ __launch_bounds__(512, 4) void attn(
    const unsigned short* __restrict__ Qg, const unsigned short* __restrict__ Kg,
    const unsigned short* __restrict__ Vtg, unsigned short* __restrict__ Yg) {
  const int S = 2048, Dh = 128;
  const float c1 = 0.08838834764831845f * 1.4426950408889634f;  // scale*log2e
  const float NEG_BIG = -3.0e38f;
  __shared__ __bf16 Ks[2][64 * 128];   // K tile, swizzled chunks, no pad
  __shared__ __bf16 Vs[2][128 * 64];   // V^T tile, swizzled chunks, no pad
  __shared__ __bf16 Ps[8][16 * 64];    // per-wave P [16 q][64 k], swizzled

  int wg = blockIdx.x;
  int lg = (wg & 7) * 64 + (wg >> 3);  // 512 blocks, 512%8==0 (bijective)
  int qtp = lg & 7;                    // 8 q-pair slots
  int bh = lg >> 3;
  const int t = threadIdx.x, lane = t & 63, w = t >> 6;
  const int l15 = lane & 15, l4 = lane >> 4;
  const unsigned short* Qb = Qg + (size_t)bh * S * Dh;
  const unsigned short* Kb = Kg + (size_t)bh * S * Dh;
  const unsigned short* Vb = Vtg + (size_t)bh * Dh * S;
  __bf16* Pw = Ps[w];
  int b = bh >> 4, h = bh & 15;
  const floatx4 zf = {0.f, 0.f, 0.f, 0.f};

  #pragma unroll 1
  for (int half = 0; half < 2; half++) {
    int jq = half ? qtp : (15 - qtp);  // pair long+short: 34 tiles per block
    int qb0 = jq * 128;
    int qrow_base = qb0 + w * 16;
    bf16x8 qf[4];
    #pragma unroll
    for (int kk = 0; kk < 4; kk++)
      qf[kk] = *(const bf16x8*)(
          &Qb[(size_t)(qrow_base + l15) * Dh + kk * 32 + l4 * 8]);
    floatx4 accO[8];
    #pragma unroll
    for (int nd = 0; nd < 8; nd++) accO[nd] = zf;
    float mst = NEG_BIG, lst = 0.f;    // per-lane: q = qrow_base + l15

    int ntiles = 2 * jq + 2;
    int cur = 0;
    attn_stage(Kb, Vb, Ks[0], Vs[0], 0, lane, w);
    __syncthreads();                   // vmcnt(0) drain + barrier: tile 0 ready

    #pragma unroll 1
    for (int kt = 0; kt < ntiles; kt++) {
      if (kt + 1 < ntiles)             // async prefetch into other buffer
        attn_stage(Kb, Vb, Ks[cur ^ 1], Vs[cur ^ 1], (kt + 1) * 64, lane, w);

      const __bf16* Kcur = Ks[cur];
      const __bf16* Vcur = Vs[cur];
      floatx4 sc[4];                   // sc[ni][r]: key=ni*16+l4*4+r, q=l15
      #pragma unroll
      for (int ni = 0; ni < 4; ni++) sc[ni] = zf;
      __builtin_amdgcn_s_setprio(1);
      #pragma unroll
      for (int kk = 0; kk < 4; kk++) { // swapped QK^T over D=128
        bf16x8 kf[4];
        #pragma unroll
        for (int ni = 0; ni < 4; ni++) {
          int row = ni * 16 + l15;
          kf[ni] = *(const bf16x8*)(
              &Kcur[row * 128 + (((kk * 4 + l4) ^ (l15 & 7)) << 3)]);
        }
        #pragma unroll
        for (int ni = 0; ni < 4; ni++)
          sc[ni] = __builtin_amdgcn_mfma_f32_16x16x32_bf16(kf[ni], qf[kk], sc[ni], 0, 0, 0);
      }
      __builtin_amdgcn_s_setprio(0);

      if (kt >= 2 * jq) {              // only last two tiles can mask
        int kb = kt * 64 - qb0 - w * 16 - l15;
        #pragma unroll
        for (int ni = 0; ni < 4; ni++)
          #pragma unroll
          for (int r = 0; r < 4; r++)
            if (kb + ni * 16 + l4 * 4 + r > 0) sc[ni][r] = NEG_BIG;
      }

      // row max: in-lane over 16, then across l4 (lanes sharing l15)
      float mt = fmaxf(fmaxf(fmaxf(sc[0][0], sc[0][1]), fmaxf(sc[0][2], sc[0][3])),
                       fmaxf(fmaxf(sc[1][0], sc[1][1]), fmaxf(sc[1][2], sc[1][3])));
      mt = fmaxf(mt,
           fmaxf(fmaxf(fmaxf(sc[2][0], sc[2][1]), fmaxf(sc[2][2], sc[2][3])),
                 fmaxf(fmaxf(sc[3][0], sc[3][1]), fmaxf(sc[3][2], sc[3][3]))));
      mt = fmaxf(mt, __shfl_xor(mt, 16, 64));
      mt = fmaxf(mt, __shfl_xor(mt, 32, 64));

      if (!__all(mt <= mst + 8.0f)) {  // defer-max: rescale only on growth
        float mnew = fmaxf(mst, mt);
        float alpha = exp2f((mst - mnew) * c1);
        mst = mnew;
        lst *= alpha;
        float ar[4];
        #pragma unroll
        for (int r = 0; r < 4; r++)    // alpha for accO row q=l4*4+r lives
          ar[r] = __shfl(alpha, l4 * 20 + r, 64);  // at lane l15=l4*4+r
        #pragma unroll
        for (int nd = 0; nd < 8; nd++)
          #pragma unroll
          for (int r = 0; r < 4; r++) accO[nd][r] *= ar[r];
      }

      float mc = mst * c1;
      float p[4][4];
      float rs = 0.f;
      #pragma unroll
      for (int ni = 0; ni < 4; ni++)
        #pragma unroll
        for (int r = 0; r < 4; r++) {
          p[ni][r] = exp2f(sc[ni][r] * c1 - mc);
          rs += p[ni][r];
        }
      rs += __shfl_xor(rs, 16, 64);
      rs += __shfl_xor(rs, 32, 64);
      lst += rs;

      // pack P -> per-wave LDS: block s=ni*4+l4 (keys 4s..4s+3) at
      // byte l15*128 + ((s>>1)^(l15&7))*16 + (s&1)*8
      #pragma unroll
      for (int ni = 0; ni < 4; ni++) {
        uint2 dw;
        dw.x = cvt_pk_bf16(p[ni][0], p[ni][1]);
        dw.y = cvt_pk_bf16(p[ni][2], p[ni][3]);
        int s = ni * 4 + l4;
        *(uint2*)(&Pw[l15 * 64 + (((s >> 1) ^ (l15 & 7)) << 3) + ((s & 1) << 2)]) = dw;
      }

      __builtin_amdgcn_s_setprio(1);
      #pragma unroll
      for (int kk = 0; kk < 2; kk++) {  // PV: A=P[q][k], B=V^T
        bf16x8 pf = *(const bf16x8*)(
            &Pw[l15 * 64 + (((kk * 4 + l4) ^ (l15 & 7)) << 3)]);
        #pragma unroll
        for (int nd = 0; nd < 8; nd++) {
          int row = nd * 16 + l15;
          bf16x8 vf = *(const bf16x8*)(
              &Vcur[row * 64 + (((kk * 4 + l4) ^ (l15 & 7)) << 3)]);
          accO[nd] = __builtin_amdgcn_mfma_f32_16x16x32_bf16(pf, vf, accO[nd], 0, 0, 0);
        }
      }
      __builtin_amdgcn_s_setprio(0);
      __syncthreads();   // vmcnt(0): prefetch landed; all reads of cur done
      cur ^= 1;
    }

    float invl = 1.0f / lst;
    float ivr[4];
    #pragma unroll
    for (int r = 0; r < 4; r++)
      ivr[r] = __shfl(invl, l4 * 20 + r, 64);   // state lane for q=l4*4+r
    #pragma unroll
    for (int r = 0; r < 4; r++) {
      int srow = qrow_base + l4 * 4 + r;
      size_t rowbase = ((size_t)(b * 2048 + srow)) * 2048 + h * 128;
      #pragma unroll
      for (int nd = 0; nd < 8; nd++)
        Yg[rowbase + nd * 16 + l15] = f2bf(accO[nd][r] * ivr[r]);
    }
  }
}

// ---- GEMM2: out(fp32) = y(bf16) @ w_projT(bf16) + b_proj(fp32)
__global__ __launch_bounds__(512, 2) void gemm_proj(
    const unsigned short* __restrict__ Yin, const unsigned short* __restrict__ WT,
    const float* __restrict__ bias, float* __restrict__ Og) {
  __shared__ unsigned short As[2][256 * 64];
  __shared__ unsigned short Bs[2][256 * 64];
  int lg = blockIdx.x;
  int bn = lg % 8, bm = lg / 8;                 // N=2048 -> 8, M=8192 -> 32
  int m0 = bm * 256, n0 = bn * 256;
  floatx4 acc[8][4];
  gemm_bt_256(Yin, WT, 2048, m0, n0, As[0], Bs[0], acc);

  const int t = threadIdx.x, lane = t & 63, w = t >> 6;
  const int wr = w >> 2, wc = w & 3;
  const int l15 = lane & 15, l4 = lane >> 4;
  float bv[4];
  #pragma unroll
  for (int ni = 0; ni < 4; ni++)
    bv[ni] = bias[n0 + wc * 64 + ni * 16 + l15];
  #pragma unroll
  for (int mi = 0; mi < 8; mi++)
    #pragma unroll
    for (int ni = 0; ni < 4; ni++)
      #pragma unroll
      for (int r = 0; r < 4; r++)
        Og[(size_t)(m0 + wr * 128 + mi * 16 + l4 * 4 + r) * 2048 +
           n0 + wc * 64 + ni * 16 + l15] = acc[mi][ni][r] + bv[ni];
}

extern "C" void kernel_launch(void* const* d_in, const int* in_sizes, int n_in,
                              void* d_out, int out_size, void* d_ws, size_t ws_size,
                              hipStream_t stream) {
  const float* x      = (const float*)d_in[0]; // [4,2048,2048] fp32
  const float* w_qkv  = (const float*)d_in[1]; // [2048,6144] fp32
  const float* b_qkv  = (const float*)d_in[2]; // [6144] fp32
  const float* w_proj = (const float*)d_in[3]; // [2048,2048] fp32
  const float* b_proj = (const float*)d_in[4]; // [2048] fp32
  float* out = (float*)d_out;                  // [4,2048,2048] fp32 (64 MiB)
  char* ws = (char*)d_ws;

  // d_out doubles as mid-pipeline scratch (fully overwritten by gemm_proj):
  //   Q bf16 at d_out[0,32M), K bf16 at d_out[32M,64M)
  // ws (88 MiB peak), lifetime-shared:
  //   [0,32M):  Vt bf16 [B,H,D,S]
  //   [32,64M): Xbf bf16 (cvt_x -> gemm_qkv), then Y bf16 (attn -> gemm_proj)
  //   [64,88M): WqT bf16 [6144,2048], later WpT bf16 [2048,2048]
  unsigned short* Q   = (unsigned short*)d_out;
  unsigned short* Kt  = (unsigned short*)((char*)d_out + 33554432);
  unsigned short* Vt  = (unsigned short*)(ws);
  unsigned short* Xbf = (unsigned short*)(ws + 33554432);
  unsigned short* Y   = (unsigned short*)(ws + 33554432);
  unsigned short* WqT = (unsigned short*)(ws + 67108864);
  unsigned short* WpT = (unsigned short*)(ws + 67108864);

  cvt_bf16<<<dim3(8192), 256, 0, stream>>>(x, Xbf);                    // 16M elems
  transpose_cvt<<<dim3(192, 64), 256, 0, stream>>>(w_qkv, WqT, 2048, 6144);
  gemm_qkv<<<dim3(768), 512, 0, stream>>>(Xbf, WqT, b_qkv, Q, Kt, Vt);
  attn<<<dim3(512), 512, 0, stream>>>(Q, Kt, Vt, Y);
  transpose_cvt<<<dim3(64, 64), 256, 0, stream>>>(w_proj, WpT, 2048, 2048);
  gemm_proj<<<dim3(256), 512, 0, stream>>>(Y, WpT, b_proj, out);
}